// Round 11
// baseline (72.064 us; speedup 1.0000x reference)
//
#include <hip/hip_runtime.h>

#define HW_PIX  114688   // 256*448
#define W_IMG   448
#define C_CH    64
#define NCAM    6
#define NCELL   28800    // 240*120
#define ZL      6
#define LVOX    172800   // ZL*NCELL
#define SEG_PX  1024
#define NSEG    (HW_PIX / SEG_PX)    // 112

typedef float vfloat4 __attribute__((ext_vector_type(4)));

// ---------------------------------------------------------------------------
// Pass 0: per-pixel coverage byte-mask (idempotent; poison-safe).
// ---------------------------------------------------------------------------
__global__ __launch_bounds__(256) void vp_coverage(
    const int* __restrict__ uu, const int* __restrict__ vv,
    const int* __restrict__ valid, unsigned char* __restrict__ mask)
{
    const int idx = blockIdx.x * 256 + threadIdx.x;
    if (idx >= NCAM * LVOX) return;
    if (valid[idx]) {
        const int cam = idx / LVOX;
        mask[(size_t)cam * HW_PIX + vv[idx] * W_IMG + uu[idx]] = 1;
    }
}

static __device__ __forceinline__ unsigned int byte_of(unsigned int a, int k) {
    return (a >> (8 * k)) & 0xffu;
}

// ---------------------------------------------------------------------------
// Pass 1: transpose+quantize [C][HW] f32 -> [HW][64] int8, scale per
// (cam, channel, 1024-px segment).
// LONG-RUN + HIGH-OCCUPANCY: block = (cam, 16-ch group, 1024-px seg).
// Wave w owns 4 channel rows; all 16 loads (4 rows x 4KB contiguous runs)
// issued before any use. Register 4x4 byte-transpose -> ds_write_b128 into
// px-major int8 planes (17KB LDS -> ~4 blocks/CU). The 4 cg-blocks of one
// (cam,seg) share low bid bits -> same XCD -> 16B partial lines merge in L2.
// ---------------------------------------------------------------------------
__global__ __launch_bounds__(256, 4) void vp_transpose_q8(
    const float* __restrict__ fish, const float* __restrict__ pv,
    const float* __restrict__ front, const unsigned char* __restrict__ mask,
    signed char* __restrict__ featsQ, float* __restrict__ scaleArr)
{
    // bid bits: [hi | cg(2b) | lo(3b)] -> 4 cg-blocks of one (cam,seg)
    // share lo bits => same XCD under round-robin dispatch.
    const int bid    = blockIdx.x;                  // 0..2687
    const int camseg = ((bid >> 5) << 3) | (bid & 7);   // 0..671
    const int cg     = (bid >> 3) & 3;              // channel group 0..3
    const int cam    = camseg / NSEG;
    const int seg    = camseg % NSEG;
    const int pix0   = seg * SEG_PX;
    const int c0     = cg * 16;

    const float* src = (cam < 4) ? (fish + (size_t)cam * C_CH * HW_PIX)
                                 : ((cam == 4) ? pv : front);

    __shared__ unsigned int planes[4][SEG_PX];      // 16KB: plane w = ch w*4..+3
    __shared__ unsigned int m_s[SEG_PX / 4];        // 1KB mask bytes

    const int tid = threadIdx.x;
    const int w   = tid >> 6;                       // wave 0..3
    const int l   = tid & 63;

    m_s[tid] = ((const unsigned int*)(mask + (size_t)cam * HW_PIX + pix0))[tid];

    // Issue ALL 16 row-segment loads (4 channels x 4KB contiguous each).
    // Iteration i covers px [i*256, i*256+256); lane l covers px i*256+l*4.
    float4 f[4][4];
    #pragma unroll
    for (int j = 0; j < 4; ++j) {
        const float* rp = src + (size_t)(c0 + w * 4 + j) * HW_PIX + pix0;
        #pragma unroll
        for (int i = 0; i < 4; ++i)
            f[j][i] = *reinterpret_cast<const float4*>(rp + i * 256 + l * 4);
    }

    // Per-channel scale, quantize, pack px-major u32 per channel.
    unsigned int p[4][4];                           // [j][i]: 4 px bytes, ch j
    #pragma unroll
    for (int j = 0; j < 4; ++j) {
        float m = 0.0f;
        #pragma unroll
        for (int i = 0; i < 4; ++i) {
            const float4 g = f[j][i];
            m = fmaxf(m, fmaxf(fmaxf(fabsf(g.x), fabsf(g.y)),
                               fmaxf(fabsf(g.z), fabsf(g.w))));
        }
        #pragma unroll
        for (int o = 32; o > 0; o >>= 1) m = fmaxf(m, __shfl_xor(m, o));
        const float inv = (m > 0.0f) ? (127.0f / m) : 0.0f;
        if (l == 0)
            scaleArr[((size_t)cam * NSEG + seg) * 64 + c0 + w * 4 + j] =
                m * (1.0f / 127.0f);
        #pragma unroll
        for (int i = 0; i < 4; ++i) {
            const float4 g = f[j][i];
            int q0 = (int)rintf(g.x * inv);
            int q1 = (int)rintf(g.y * inv);
            int q2 = (int)rintf(g.z * inv);
            int q3 = (int)rintf(g.w * inv);
            q0 = q0 > 127 ? 127 : (q0 < -127 ? -127 : q0);
            q1 = q1 > 127 ? 127 : (q1 < -127 ? -127 : q1);
            q2 = q2 > 127 ? 127 : (q2 < -127 ? -127 : q2);
            q3 = q3 > 127 ? 127 : (q3 < -127 ? -127 : q3);
            p[j][i] = ((unsigned int)(q0 & 0xff))       |
                      ((unsigned int)(q1 & 0xff) << 8)  |
                      ((unsigned int)(q2 & 0xff) << 16) |
                      ((unsigned int)(q3 & 0xff) << 24);
        }
    }

    // 4x4 register byte-transpose per px-quad; one ds_write_b128 per quad.
    #pragma unroll
    for (int i = 0; i < 4; ++i) {
        uint4 q;
        unsigned int* qq = &q.x;
        #pragma unroll
        for (int k = 0; k < 4; ++k)
            qq[k] = byte_of(p[0][i], k)        |
                    (byte_of(p[1][i], k) << 8) |
                    (byte_of(p[2][i], k) << 16)|
                    (byte_of(p[3][i], k) << 24);
        // words px..px+3 of plane w, px = i*256 + l*4  (16B aligned)
        *reinterpret_cast<uint4*>(&planes[w][i * 256 + l * 4]) = q;
    }
    __syncthreads();

    // Write-out: thread handles one px per iter; 16B (ch c0..c0+15) per px,
    // coverage-masked at pixel granularity.
    signed char* dstc = featsQ + ((size_t)cam * HW_PIX + pix0) * 64 + c0;
    #pragma unroll
    for (int it = 0; it < 4; ++it) {
        const int px = it * 256 + tid;
        const unsigned int mb = (m_s[px >> 2] >> ((px & 3) * 8)) & 0xffu;
        if (mb != 1u) continue;
        uint4 o;
        o.x = planes[0][px];
        o.y = planes[1][px];
        o.z = planes[2][px];
        o.w = planes[3][px];
        *reinterpret_cast<uint4*>(dstc + (size_t)px * 64) = o;
    }
}

// ---------------------------------------------------------------------------
// Pass 2: gather (int8 [HW][64], per-(c,seg) scales) + weight + z-sum + write.
// Per valid voxel: ONE 64B line; 32B of scales per lane from the L2-resident
// 172KB scale table. Output stores nontemporal.
// ---------------------------------------------------------------------------
__global__ __launch_bounds__(256) void vp_gather_q8(
    const signed char* __restrict__ featsQ, const float* __restrict__ scaleArr,
    const int*   __restrict__ uu, const int* __restrict__ vv,
    const int*   __restrict__ valid, const float* __restrict__ density,
    float* __restrict__ out)
{
    const int bid   = blockIdx.x;                   // 0..2699
    const int cam   = bid / (NCELL / 64);
    const int cell0 = (bid % (NCELL / 64)) * 64;
    const int tid   = threadIdx.x;

    __shared__ int   p_s[ZL * 64];
    __shared__ float w_s[ZL * 64];
    __shared__ float acc_s[64][65];

    for (int v = tid; v < ZL * 64; v += 256) {
        int z  = v >> 6;
        int cl = v & 63;
        size_t l = (size_t)cam * LVOX + (size_t)z * NCELL + cell0 + cl;
        p_s[v] = vv[l] * W_IMG + uu[l];
        w_s[v] = valid[l] ? density[l] : 0.0f;
    }
    __syncthreads();

    const int g  = tid >> 3;                        // group 0..31
    const int la = tid & 7;                         // lane-in-group 0..7
    const signed char* base  = featsQ + (size_t)cam * HW_PIX * 64 + la * 8;
    const float*       sbase = scaleArr + (size_t)cam * NSEG * 64 + la * 8;

    float acc[2][8];
    #pragma unroll
    for (int ci = 0; ci < 2; ++ci)
        #pragma unroll
        for (int k = 0; k < 8; ++k) acc[ci][k] = 0.0f;

    #pragma unroll
    for (int ci = 0; ci < 2; ++ci) {
        const int cl = g + ci * 32;
        #pragma unroll
        for (int z = 0; z < ZL; ++z) {
            const int v = z * 64 + cl;
            const float w = w_s[v];
            if (w != 0.0f) {
                const int p = p_s[v];
                const uint2 q = *reinterpret_cast<const uint2*>(
                    base + (size_t)p * 64);
                const float* sp = sbase + ((size_t)(p >> 10) << 6);
                const float4 s0 = *reinterpret_cast<const float4*>(sp);
                const float4 s1 = *reinterpret_cast<const float4*>(sp + 4);
                acc[ci][0] += (float)((int)(signed char)(q.x      )) * (s0.x * w);
                acc[ci][1] += (float)((int)(signed char)(q.x >>  8)) * (s0.y * w);
                acc[ci][2] += (float)((int)(signed char)(q.x >> 16)) * (s0.z * w);
                acc[ci][3] += (float)((int)(signed char)(q.x >> 24)) * (s0.w * w);
                acc[ci][4] += (float)((int)(signed char)(q.y      )) * (s1.x * w);
                acc[ci][5] += (float)((int)(signed char)(q.y >>  8)) * (s1.y * w);
                acc[ci][6] += (float)((int)(signed char)(q.y >> 16)) * (s1.z * w);
                acc[ci][7] += (float)((int)(signed char)(q.y >> 24)) * (s1.w * w);
            }
        }
    }

    #pragma unroll
    for (int ci = 0; ci < 2; ++ci) {
        const int cl = g + ci * 32;
        #pragma unroll
        for (int k = 0; k < 8; ++k)
            acc_s[cl][la * 8 + k] = acc[ci][k];
    }
    __syncthreads();

    #pragma unroll
    for (int i = 0; i < 4; ++i) {
        int e   = i * 256 + tid;
        int c   = e >> 4;
        int cl4 = e & 15;
        vfloat4 f;
        f.x = acc_s[cl4 * 4 + 0][c];
        f.y = acc_s[cl4 * 4 + 1][c];
        f.z = acc_s[cl4 * 4 + 2][c];
        f.w = acc_s[cl4 * 4 + 3][c];
        __builtin_nontemporal_store(f, reinterpret_cast<vfloat4*>(
            out + ((size_t)cam * C_CH + c) * NCELL + cell0 + cl4 * 4));
    }
}

// ---------------------------------------------------------------------------
// Fallback (if d_ws too small): direct strided gather from native layout.
// ---------------------------------------------------------------------------
__global__ __launch_bounds__(256) void vp_fallback_kernel(
    const float* __restrict__ fish, const float* __restrict__ pv,
    const float* __restrict__ front,
    const int*   __restrict__ uu, const int* __restrict__ vv,
    const int*   __restrict__ valid, const float* __restrict__ density,
    float* __restrict__ out)
{
    const int idx = blockIdx.x * 256 + threadIdx.x;
    if (idx >= NCAM * C_CH * NCELL) return;
    const int cell = idx % NCELL;
    const int c    = (idx / NCELL) % C_CH;
    const int cam  = idx / (NCELL * C_CH);
    const float* src = (cam < 4)
        ? (fish + ((size_t)cam * C_CH + c) * HW_PIX)
        : (((cam == 4) ? pv : front) + (size_t)c * HW_PIX);
    float acc = 0.0f;
    for (int z = 0; z < ZL; ++z) {
        const size_t l = (size_t)cam * LVOX + (size_t)z * NCELL + cell;
        if (valid[l]) {
            acc += src[vv[l] * W_IMG + uu[l]] * density[l];
        }
    }
    out[idx] = acc;
}

extern "C" void kernel_launch(void* const* d_in, const int* in_sizes, int n_in,
                              void* d_out, int out_size, void* d_ws, size_t ws_size,
                              hipStream_t stream) {
    const float* fish    = (const float*)d_in[0];
    const float* pv      = (const float*)d_in[1];
    const float* front   = (const float*)d_in[2];
    const int*   uu      = (const int*)d_in[3];
    const int*   vv      = (const int*)d_in[4];
    const int*   valid   = (const int*)d_in[5];
    const float* density = (const float*)d_in[6];
    float*       out     = (float*)d_out;

    const size_t featsBytes = (size_t)NCAM * HW_PIX * 64;              // 44.04 MB
    const size_t scaleBytes = (size_t)NCAM * NSEG * 64 * sizeof(float);// 172 KB
    const size_t maskBytes  = (size_t)NCAM * HW_PIX;                   // 688 KB
    const size_t need = featsBytes + scaleBytes + maskBytes;

    if (ws_size >= need) {
        signed char*   featsQ   = (signed char*)d_ws;
        float*         scaleArr = (float*)((char*)d_ws + featsBytes);
        unsigned char* mask     = (unsigned char*)((char*)d_ws + featsBytes + scaleBytes);
        vp_coverage<<<(NCAM * LVOX + 255) / 256, 256, 0, stream>>>(
            uu, vv, valid, mask);
        vp_transpose_q8<<<NCAM * NSEG * 4, 256, 0, stream>>>(
            fish, pv, front, mask, featsQ, scaleArr);
        vp_gather_q8<<<NCAM * (NCELL / 64), 256, 0, stream>>>(
            featsQ, scaleArr, uu, vv, valid, density, out);
    } else {
        vp_fallback_kernel<<<(NCAM * C_CH * NCELL + 255) / 256, 256, 0, stream>>>(
            fish, pv, front, uu, vv, valid, density, out);
    }
}

// Round 12
// 62.676 us; speedup vs baseline: 1.1498x; 1.1498x over previous
//
#include <hip/hip_runtime.h>
#include <hip/hip_fp16.h>

#define HW_PIX  114688   // 256*448
#define W_IMG   448
#define C_CH    64
#define NCAM    6
#define NCELL   28800    // 240*120
#define ZL      6
#define LVOX    172800   // ZL*NCELL
#define TILE_PX 256
#define NTILES  (HW_PIX / TILE_PX)   // 448

typedef float vfloat4 __attribute__((ext_vector_type(4)));

// ---------------------------------------------------------------------------
// Pass 0: per-pixel coverage byte-mask. mask[cam][p] == 1 iff some valid
// voxel gathers pixel p. Idempotent (only writes 1s at fixed addresses) ->
// deterministic across graph replays; 0xAA poison at uncovered px merely
// reads as "not ==1" (skip).
// ---------------------------------------------------------------------------
__global__ __launch_bounds__(256) void vp_coverage(
    const int* __restrict__ uu, const int* __restrict__ vv,
    const int* __restrict__ valid, unsigned char* __restrict__ mask)
{
    const int idx = blockIdx.x * 256 + threadIdx.x;
    if (idx >= NCAM * LVOX) return;
    if (valid[idx]) {
        const int cam = idx / LVOX;
        mask[(size_t)cam * HW_PIX + vv[idx] * W_IMG + uu[idx]] = 1;
    }
}

// ---------------------------------------------------------------------------
// Pass 1: transpose+quantize  [C][HW] (f32) -> [HW][64] (int8), one f32 scale
// per (cam, 256-px tile). Stores are SKIPPED for uncovered pixels (each
// pixel = exactly one 64B line) -> ~47% write-byte cut.
// ---------------------------------------------------------------------------
__global__ __launch_bounds__(256) void vp_transpose_q8(
    const float* __restrict__ fish, const float* __restrict__ pv,
    const float* __restrict__ front, const unsigned char* __restrict__ mask,
    signed char* __restrict__ featsQ, float* __restrict__ scaleArr)
{
    const int bid  = blockIdx.x;                    // 0..2687
    const int cam  = bid / NTILES;
    const int tile = bid % NTILES;
    const int pix0 = tile * TILE_PX;

    const float* src = (cam < 4) ? (fish + (size_t)cam * C_CH * HW_PIX)
                                 : ((cam == 4) ? pv : front);

    __shared__ __half t[64][260];                   // 520B stride
    __shared__ float  wmax[4];
    __shared__ unsigned int m_s[TILE_PX / 4];       // 256 mask bytes

    const int tid = threadIdx.x;
    const int w   = tid >> 6;                       // wave 0..3
    const int l   = tid & 63;

    if (tid < TILE_PX / 4)
        m_s[tid] = *((const unsigned int*)(mask + (size_t)cam * HW_PIX + pix0)
                     + tid);

    // Load 16 channel rows per wave; fp16-stage to LDS; track max|f|.
    float m = 0.0f;
    #pragma unroll
    for (int i = 0; i < 16; ++i) {
        const int c = w * 16 + i;
        const float4 f = *reinterpret_cast<const float4*>(
            src + (size_t)c * HW_PIX + pix0 + l * 4);
        m = fmaxf(m, fmaxf(fmaxf(fabsf(f.x), fabsf(f.y)),
                           fmaxf(fabsf(f.z), fabsf(f.w))));
        __half2 h01 = __floats2half2_rn(f.x, f.y);
        __half2 h23 = __floats2half2_rn(f.z, f.w);
        *reinterpret_cast<__half2*>(&t[c][l * 4 + 0]) = h01;
        *reinterpret_cast<__half2*>(&t[c][l * 4 + 2]) = h23;
    }

    // Tile max: wave shuffle-reduce, then cross-wave via LDS.
    #pragma unroll
    for (int o = 32; o > 0; o >>= 1) m = fmaxf(m, __shfl_xor(m, o));
    if (l == 0) wmax[w] = m;
    __syncthreads();
    const float tmax = fmaxf(fmaxf(wmax[0], wmax[1]), fmaxf(wmax[2], wmax[3]));
    const float inv  = (tmax > 0.0f) ? (127.0f / tmax) : 0.0f;
    if (tid == 0) scaleArr[cam * NTILES + tile] = tmax * (1.0f / 127.0f);

    // Store: thread handles a pixel PAIR x 8-channel group; store only
    // covered pixels (64B line == one pixel).
    signed char* dstc = featsQ + ((size_t)cam * HW_PIX + pix0) * 64;
    #pragma unroll
    for (int it = 0; it < 4; ++it) {
        const int e    = it * 256 + tid;            // 0..1023
        const int pair = e >> 3;                    // 0..127
        const int g    = e & 7;                     // 8-ch group 0..7
        const int px   = pair * 2;
        const unsigned int wd = m_s[px >> 2] >> ((px & 2) * 8);
        const bool c0 = (wd & 0x000000ffu) == 1u;
        const bool c1 = (wd & 0x0000ff00u) == 0x100u;
        if (!(c0 | c1)) continue;
        uint2 o0, o1;
        o0.x = o0.y = o1.x = o1.y = 0u;
        #pragma unroll
        for (int k = 0; k < 8; ++k) {
            const __half2 h2 = *reinterpret_cast<const __half2*>(
                &t[g * 8 + k][px]);                 // halves for px, px+1
            const float v0 = __low2float(h2);
            const float v1 = __high2float(h2);
            int q0 = (int)rintf(v0 * inv);
            int q1 = (int)rintf(v1 * inv);
            q0 = q0 > 127 ? 127 : (q0 < -127 ? -127 : q0);
            q1 = q1 > 127 ? 127 : (q1 < -127 ? -127 : q1);
            const unsigned int b0 = (unsigned int)(q0 & 0xff);
            const unsigned int b1 = (unsigned int)(q1 & 0xff);
            if (k < 4) { o0.x |= b0 << (8 * k);       o1.x |= b1 << (8 * k); }
            else       { o0.y |= b0 << (8 * (k - 4)); o1.y |= b1 << (8 * (k - 4)); }
        }
        signed char* dp = dstc + (size_t)px * 64 + g * 8;
        if (c0) *reinterpret_cast<uint2*>(dp)      = o0;
        if (c1) *reinterpret_cast<uint2*>(dp + 64) = o1;
    }
}

// ---------------------------------------------------------------------------
// Pass 2: gather (int8, [HW][64], per-tile scale) + weight + z-sum + write.
// Block = (cam, 64-cell tile). 256 threads = 32 groups x 8 lanes.
// Per valid voxel: ONE 64B line. Output stores nontemporal.
// ---------------------------------------------------------------------------
__global__ __launch_bounds__(256) void vp_gather_q8(
    const signed char* __restrict__ featsQ, const float* __restrict__ scaleArr,
    const int*   __restrict__ uu, const int* __restrict__ vv,
    const int*   __restrict__ valid, const float* __restrict__ density,
    float* __restrict__ out)
{
    const int bid   = blockIdx.x;                   // 0..2699
    const int cam   = bid / (NCELL / 64);
    const int cell0 = (bid % (NCELL / 64)) * 64;
    const int tid   = threadIdx.x;

    __shared__ int   p_s[ZL * 64];
    __shared__ float w_s[ZL * 64];
    __shared__ float s_scale[NTILES];               // 448 per-tile scales
    __shared__ float acc_s[64][65];

    for (int j = tid; j < NTILES; j += 256)
        s_scale[j] = scaleArr[cam * NTILES + j];
    for (int v = tid; v < ZL * 64; v += 256) {
        int z  = v >> 6;
        int cl = v & 63;
        size_t l = (size_t)cam * LVOX + (size_t)z * NCELL + cell0 + cl;
        p_s[v] = vv[l] * W_IMG + uu[l];
        w_s[v] = valid[l] ? density[l] : 0.0f;
    }
    __syncthreads();

    const int g  = tid >> 3;                        // group 0..31
    const int la = tid & 7;                         // lane-in-group 0..7
    const signed char* base = featsQ + (size_t)cam * HW_PIX * 64 + la * 8;

    float acc[2][8];
    #pragma unroll
    for (int ci = 0; ci < 2; ++ci)
        #pragma unroll
        for (int k = 0; k < 8; ++k) acc[ci][k] = 0.0f;

    #pragma unroll
    for (int ci = 0; ci < 2; ++ci) {
        const int cl = g + ci * 32;
        #pragma unroll
        for (int z = 0; z < ZL; ++z) {
            const int v = z * 64 + cl;
            const float w = w_s[v];
            if (w != 0.0f) {
                const int p = p_s[v];
                const uint2 q = *reinterpret_cast<const uint2*>(
                    base + (size_t)p * 64);
                const float sw = w * s_scale[p >> 8];
                acc[ci][0] += (float)((int)(signed char)(q.x      )) * sw;
                acc[ci][1] += (float)((int)(signed char)(q.x >>  8)) * sw;
                acc[ci][2] += (float)((int)(signed char)(q.x >> 16)) * sw;
                acc[ci][3] += (float)((int)(signed char)(q.x >> 24)) * sw;
                acc[ci][4] += (float)((int)(signed char)(q.y      )) * sw;
                acc[ci][5] += (float)((int)(signed char)(q.y >>  8)) * sw;
                acc[ci][6] += (float)((int)(signed char)(q.y >> 16)) * sw;
                acc[ci][7] += (float)((int)(signed char)(q.y >> 24)) * sw;
            }
        }
    }

    // channel = la*8 + k
    #pragma unroll
    for (int ci = 0; ci < 2; ++ci) {
        const int cl = g + ci * 32;
        #pragma unroll
        for (int k = 0; k < 8; ++k)
            acc_s[cl][la * 8 + k] = acc[ci][k];
    }
    __syncthreads();

    #pragma unroll
    for (int i = 0; i < 4; ++i) {
        int e   = i * 256 + tid;
        int c   = e >> 4;
        int cl4 = e & 15;
        vfloat4 f;
        f.x = acc_s[cl4 * 4 + 0][c];
        f.y = acc_s[cl4 * 4 + 1][c];
        f.z = acc_s[cl4 * 4 + 2][c];
        f.w = acc_s[cl4 * 4 + 3][c];
        __builtin_nontemporal_store(f, reinterpret_cast<vfloat4*>(
            out + ((size_t)cam * C_CH + c) * NCELL + cell0 + cl4 * 4));
    }
}

// ---------------------------------------------------------------------------
// Fallback (if d_ws too small): direct strided gather from native layout.
// ---------------------------------------------------------------------------
__global__ __launch_bounds__(256) void vp_fallback_kernel(
    const float* __restrict__ fish, const float* __restrict__ pv,
    const float* __restrict__ front,
    const int*   __restrict__ uu, const int* __restrict__ vv,
    const int*   __restrict__ valid, const float* __restrict__ density,
    float* __restrict__ out)
{
    const int idx = blockIdx.x * 256 + threadIdx.x;
    if (idx >= NCAM * C_CH * NCELL) return;
    const int cell = idx % NCELL;
    const int c    = (idx / NCELL) % C_CH;
    const int cam  = idx / (NCELL * C_CH);
    const float* src = (cam < 4)
        ? (fish + ((size_t)cam * C_CH + c) * HW_PIX)
        : (((cam == 4) ? pv : front) + (size_t)c * HW_PIX);
    float acc = 0.0f;
    for (int z = 0; z < ZL; ++z) {
        const size_t l = (size_t)cam * LVOX + (size_t)z * NCELL + cell;
        if (valid[l]) {
            acc += src[vv[l] * W_IMG + uu[l]] * density[l];
        }
    }
    out[idx] = acc;
}

extern "C" void kernel_launch(void* const* d_in, const int* in_sizes, int n_in,
                              void* d_out, int out_size, void* d_ws, size_t ws_size,
                              hipStream_t stream) {
    const float* fish    = (const float*)d_in[0];
    const float* pv      = (const float*)d_in[1];
    const float* front   = (const float*)d_in[2];
    const int*   uu      = (const int*)d_in[3];
    const int*   vv      = (const int*)d_in[4];
    const int*   valid   = (const int*)d_in[5];
    const float* density = (const float*)d_in[6];
    float*       out     = (float*)d_out;

    const size_t featsBytes = (size_t)NCAM * HW_PIX * 64;          // 44.04 MB
    const size_t scaleBytes = (size_t)NCAM * NTILES * sizeof(float);
    const size_t maskBytes  = (size_t)NCAM * HW_PIX;               // 688 KB
    const size_t need = featsBytes + scaleBytes + maskBytes;

    if (ws_size >= need) {
        signed char*   featsQ   = (signed char*)d_ws;
        float*         scaleArr = (float*)((char*)d_ws + featsBytes);
        unsigned char* mask     = (unsigned char*)((char*)d_ws + featsBytes + scaleBytes);
        vp_coverage<<<(NCAM * LVOX + 255) / 256, 256, 0, stream>>>(
            uu, vv, valid, mask);
        vp_transpose_q8<<<NCAM * NTILES, 256, 0, stream>>>(
            fish, pv, front, mask, featsQ, scaleArr);
        vp_gather_q8<<<NCAM * (NCELL / 64), 256, 0, stream>>>(
            featsQ, scaleArr, uu, vv, valid, density, out);
    } else {
        vp_fallback_kernel<<<(NCAM * C_CH * NCELL + 255) / 256, 256, 0, stream>>>(
            fish, pv, front, uu, vv, valid, density, out);
    }
}